// Round 7
// baseline (11986.971 us; speedup 1.0000x reference)
//
#include <hip/hip_runtime.h>
#include <hip/hip_fp16.h>
#include <cstddef>

#define Bb 64
#define Tt 512
#define INRAW 225
#define INPAD 240
#define Hh 256
#define G4 1024
#define Ee 512
#define NCODE 128
#define NCLS 250

typedef _Float16 half8_t __attribute__((ext_vector_type(8)));
typedef float f32x4 __attribute__((ext_vector_type(4)));

__device__ __forceinline__ float sigf(float x) { return 1.0f / (1.0f + expf(-x)); }
__device__ __forceinline__ float fsig(float x) { return __builtin_amdgcn_rcpf(1.0f + __expf(-x)); }
__device__ __forceinline__ float ftanh(float x) {
  return 2.0f * __builtin_amdgcn_rcpf(1.0f + __expf(-2.0f * x)) - 1.0f;
}

__device__ __forceinline__ void coh_store16(void* gp, half8_t v) {
  asm volatile("global_store_dwordx4 %0, %1, off sc0 sc1" :: "v"(gp), "v"(v) : "memory");
}
__device__ __forceinline__ half8_t coh_load16(const void* gp) {
  half8_t r;
  asm volatile("global_load_dwordx4 %0, %1, off sc0 sc1" : "=v"(r) : "v"(gp) : "memory");
  return r;
}

// ---------------- zero flags ----------------
__global__ __launch_bounds__(256) void zero_flags_k(int* __restrict__ p, int n) {
  int i = blockIdx.x * 256 + threadIdx.x;
  if (i < n) __hip_atomic_store(&p[i], 0, __ATOMIC_RELAXED, __HIP_MEMORY_SCOPE_AGENT);
}

// ---------------- pad copy: [M,Ks] -> [M,Kd] zero-filled ----------------
__global__ __launch_bounds__(256) void pad_copy_k(const float* __restrict__ src,
                                                  float* __restrict__ dst,
                                                  int M, int Ks, int Kd) {
  long long idx = (long long)blockIdx.x * 256 + threadIdx.x;
  if (idx >= (long long)M * Kd) return;
  int m = (int)(idx / Kd);
  int k = (int)(idx - (long long)m * Kd);
  dst[idx] = (k < Ks) ? src[(long long)m * Ks + k] : 0.0f;
}

// ------- pack W[1024,K] -> wp[k][j(0..255)][g(0..3)] fp32 (dec_bwd only) ------
__global__ __launch_bounds__(256) void pack_w_k(const float* __restrict__ W,
                                                float* __restrict__ wp, int K) {
  int idx = blockIdx.x * 256 + threadIdx.x;   // = jg*K + k
  int jg = idx / K;
  if (jg >= 1024) return;
  int k = idx - jg * K;
  int j = jg >> 2, g = jg & 3;
  wp[(((size_t)k << 8) + j) * 4 + g] = W[(size_t)(g * 256 + j) * K + k];
}

// ------- pack Whh[1024,256] fp32 -> fp16 MFMA B-fragment stream ---------------
// flat half idx = ((((wv*8+ks)*8)+zg)*64 + l)*8 + e
// value = Whh[(g*256 + u)*256 + k], zg=z*4+g, u=wv*32+z*16+(l&15), k=ks*32+(l>>4)*8+e
__global__ __launch_bounds__(256) void pack_w_frag(const float* __restrict__ W,
                                                   _Float16* __restrict__ wp) {
  int idx = blockIdx.x * 256 + threadIdx.x;   // 262144 total
  int e = idx & 7, l = (idx >> 3) & 63, zg = (idx >> 9) & 7;
  int ks = (idx >> 12) & 7, wv = (idx >> 15) & 7;
  int z = zg >> 2, g = zg & 3;
  int u = wv * 32 + z * 16 + (l & 15);
  int k = ks * 32 + (l >> 4) * 8 + e;
  wp[idx] = (_Float16)W[(size_t)(g * 256 + u) * 256 + k];
}

// ---- GEMM: C[M,N] = A[M,K] @ Bw[N,K]^T + bias[N]; fp16 out in the scan's
// per-lane fragment order (verified R4).
#define BM 128
#define BN 128
#define BKk 16
__global__ __launch_bounds__(256) void gemm_nt_bias_h(const float* __restrict__ A,
                                                      const float* __restrict__ Bw,
                                                      const float* __restrict__ bias,
                                                      __half* __restrict__ C,
                                                      int M, int N, int K) {
  __shared__ __align__(16) float As[BKk][BM];
  __shared__ __align__(16) float Bs[BKk][BN];
  const int tid = threadIdx.x;
  const int bm = blockIdx.y * BM, bn = blockIdx.x * BN;
  const int ty = tid >> 4, tx = tid & 15;
  const int srow = tid >> 1;
  const int sk = (tid & 1) * 8;

  const float* Aptr = A + (size_t)(bm + srow) * K + sk;
  const float* Bptr = Bw + (size_t)(bn + srow) * K + sk;

  float4 ra0 = *(const float4*)(Aptr);
  float4 ra1 = *(const float4*)(Aptr + 4);
  float4 rb0 = *(const float4*)(Bptr);
  float4 rb1 = *(const float4*)(Bptr + 4);

  float acc[8][8];
#pragma unroll
  for (int i = 0; i < 8; ++i)
#pragma unroll
    for (int j = 0; j < 8; ++j) acc[i][j] = 0.0f;

  for (int k0 = 0; k0 < K; k0 += BKk) {
    __syncthreads();
    As[sk + 0][srow] = ra0.x; As[sk + 1][srow] = ra0.y;
    As[sk + 2][srow] = ra0.z; As[sk + 3][srow] = ra0.w;
    As[sk + 4][srow] = ra1.x; As[sk + 5][srow] = ra1.y;
    As[sk + 6][srow] = ra1.z; As[sk + 7][srow] = ra1.w;
    Bs[sk + 0][srow] = rb0.x; Bs[sk + 1][srow] = rb0.y;
    Bs[sk + 2][srow] = rb0.z; Bs[sk + 3][srow] = rb0.w;
    Bs[sk + 4][srow] = rb1.x; Bs[sk + 5][srow] = rb1.y;
    Bs[sk + 6][srow] = rb1.z; Bs[sk + 7][srow] = rb1.w;
    __syncthreads();
    if (k0 + BKk < K) {
      ra0 = *(const float4*)(Aptr + k0 + BKk);
      ra1 = *(const float4*)(Aptr + k0 + BKk + 4);
      rb0 = *(const float4*)(Bptr + k0 + BKk);
      rb1 = *(const float4*)(Bptr + k0 + BKk + 4);
    }
#pragma unroll
    for (int kk = 0; kk < BKk; ++kk) {
      float4 aA = *(const float4*)&As[kk][ty * 8];
      float4 aB = *(const float4*)&As[kk][ty * 8 + 4];
      float4 bA = *(const float4*)&Bs[kk][tx * 8];
      float4 bB = *(const float4*)&Bs[kk][tx * 8 + 4];
      float av[8] = {aA.x, aA.y, aA.z, aA.w, aB.x, aB.y, aB.z, aB.w};
      float bv[8] = {bA.x, bA.y, bA.z, bA.w, bB.x, bB.y, bB.z, bB.w};
#pragma unroll
      for (int i = 0; i < 8; ++i)
#pragma unroll
        for (int j = 0; j < 8; ++j)
          acc[i][j] = fmaf(av[i], bv[j], acc[i][j]);
    }
  }
  float bs[8];
#pragma unroll
  for (int j = 0; j < 8; ++j) bs[j] = bias[bn + tx * 8 + j];

  // scatter into scan fragment layout:
  // half idx = ((((t*4+b)*8+w)*2+z)*64 + lane)*16 + g*4 + j
  const int col0 = bn + tx * 8;
  const int g = col0 >> 8;
  const int u0 = col0 & 255;                 // 8-aligned
  const int w_ = u0 >> 5, z_ = (u0 >> 4) & 1, l15_ = u0 & 15;
#pragma unroll
  for (int i = 0; i < 8; ++i) {
    const int row = bm + ty * 8 + i;
    const int t = row & (Tt - 1);
    const int batch = row >> 9;
    const int b_ = batch >> 4, rbq = (batch & 15) >> 2, j_ = batch & 3;
    const int lane = (rbq << 4) | l15_;
    __half* dst = C + ((((size_t)t * 4 + b_) * 8 + w_) * 2 + z_) * 1024
                    + (size_t)lane * 16 + g * 4 + j_;
#pragma unroll
    for (int jx = 0; jx < 8; ++jx) dst[jx * 16] = __float2half(acc[i][jx] + bs[jx]);
  }
}

// ------ pairwise-exchange LSTM scan: 4 blocks/dir, 8 waves (512 thr) ---------
// block (uh, rh): units [uh*128,+128), rows [rh*32,+32). Weights VGPR-resident.
// Own-half h in LDS (XOR-swizzled); partner half exchanged via coherent
// global stores/loads + relaxed flags (vmcnt(0) is the release).
__global__ __launch_bounds__(512, 2) void lstm_scan_x2(
    const half8_t* __restrict__ preA, const half8_t* __restrict__ wA,
    _Float16* __restrict__ hexA, int* __restrict__ flgA,
    const half8_t* __restrict__ preB, const half8_t* __restrict__ wB,
    _Float16* __restrict__ hexB, int* __restrict__ flgB, int nA) {
  const int isB = (blockIdx.x >= nA) ? 1 : 0;
  const half8_t* pre = isB ? preB : preA;
  const half8_t* wfrag = isB ? wB : wA;
  _Float16* hex = isB ? hexB : hexA;
  int* flg = isB ? flgB : flgA;
  const int sub = blockIdx.x - (isB ? nA : 0);
  const int uh = sub & 1, rh = sub >> 1;
  const int tid = threadIdx.x;
  const int wv = tid >> 6, l = tid & 63;
  const int l15 = l & 15, lg = l >> 4;
  const int sl = uh * 8 + wv;
  const int wvp = sl >> 1, zp = sl & 1;

  __shared__ __align__(16) char hbuf[2][32 * 256];   // [buf][row32][own unit128] fp16 swz

  // resident weights: 32 frags = 128 VGPR
  half8_t bfr[8][4];
#pragma unroll
  for (int ks = 0; ks < 8; ++ks)
#pragma unroll
    for (int g = 0; g < 4; ++g)
      bfr[ks][g] = wfrag[(size_t)((wvp * 8 + ks) * 8 + zp * 4 + g) * 64 + l];

  float c[2][4] = {{0.f, 0.f, 0.f, 0.f}, {0.f, 0.f, 0.f, 0.f}};

  auto ld_pre = [&](int t, half8_t* dst) {
#pragma unroll
    for (int rgl = 0; rgl < 2; ++rgl) {
      const size_t bb = (((size_t)t * 4 + rh * 2 + rgl) * 16 + sl) * 128 + (size_t)l * 2;
      dst[rgl * 2 + 0] = pre[bb];
      dst[rgl * 2 + 1] = pre[bb + 1];
    }
  };

#define ACC_INIT(ACC)                                                      \
  _Pragma("unroll")                                                        \
  for (int rgl = 0; rgl < 2; ++rgl)                                        \
    _Pragma("unroll")                                                      \
    for (int g = 0; g < 4; ++g)                                            \
      _Pragma("unroll")                                                    \
      for (int j = 0; j < 4; ++j)                                          \
        ACC[rgl][g][j] = (float)pc[rgl * 2 + (g >> 1)][(g & 1) * 4 + j];

#define GATES_WRITE(ACC, NXT)                                              \
  _Pragma("unroll")                                                        \
  for (int rgl = 0; rgl < 2; ++rgl)                                        \
    _Pragma("unroll")                                                      \
    for (int j = 0; j < 4; ++j) {                                          \
      float iv = fsig(ACC[rgl][0][j]);                                     \
      float fv = fsig(ACC[rgl][1][j]);                                     \
      float gv = ftanh(ACC[rgl][2][j]);                                    \
      float ov = fsig(ACC[rgl][3][j]);                                     \
      c[rgl][j] = fv * c[rgl][j] + iv * gv;                                \
      float hv = ov * ftanh(c[rgl][j]);                                    \
      const int rloc = rgl * 16 + lg * 4 + j;                              \
      const int lb = (rloc * 256 + (wv * 16 + l15) * 2) ^                  \
                     (((lg * 4 + j) & 7) << 4);                            \
      *(_Float16*)(hbuf[NXT] + lb) = (_Float16)hv;                         \
    }

  // prologue s=0: gates from pre only -> h(0) into buf0
  half8_t pc[4];
  {
    const int t0 = isB ? (Tt - 1) : 0;
    ld_pre(t0, pc);
    f32x4 acc[2][4];
    ACC_INIT(acc);
    const int t1 = isB ? (Tt - 2) : 1;
    ld_pre(t1, pc);
    GATES_WRITE(acc, 0);
  }
  __syncthreads();

  int cur = 0;
  for (int s = 1; s < Tt; ++s) {
    const int t = isB ? (Tt - 1 - s) : s;
    const int tprev = isB ? (Tt - s) : (s - 1);

    // 1. copy own h(s-1) LDS -> hex(tprev)  (coherent, issue early)
    {
      const int rr = tid >> 4, ch = tid & 15;
      const int lb = (rr * 256 + ch * 16) ^ ((rr & 7) << 4);
      half8_t v = *(const half8_t*)(hbuf[cur] + lb);
      _Float16* gp = hex + ((size_t)tprev * 64 + rh * 32 + rr) * 256 + uh * 128 + ch * 8;
      coh_store16(gp, v);
    }

    // 2. acc init from pc (pre(t))
    f32x4 acc[2][4];
    ACC_INIT(acc);

    // 3. own-half MFMA from LDS (runs in the store-ack shadow)
#pragma unroll
    for (int rgl = 0; rgl < 2; ++rgl) {
      half8_t afr[4];
#pragma unroll
      for (int kk = 0; kk < 4; ++kk) {
        const int lb = ((rgl * 16 + l15) * 256 + kk * 64 + lg * 16) ^ ((l15 & 7) << 4);
        afr[kk] = *(const half8_t*)(hbuf[cur] + lb);
      }
#pragma unroll
      for (int kk = 0; kk < 4; ++kk)
#pragma unroll
        for (int g = 0; g < 4; ++g)
          acc[rgl][g] = __builtin_amdgcn_mfma_f32_16x16x32_f16(
              afr[kk], bfr[uh * 4 + kk][g], acc[rgl][g], 0, 0, 0);
    }

    // 4. release: stores acked at coherence point, then relaxed flag
    asm volatile("s_waitcnt vmcnt(0)" ::: "memory");
    if (tid == 0)
      __hip_atomic_store(&flg[((s - 1) * 2 + rh) * 2 + uh], 1,
                         __ATOMIC_RELAXED, __HIP_MEMORY_SCOPE_AGENT);

    // 5. poll partner's flag
    {
      int* fp = &flg[((s - 1) * 2 + rh) * 2 + (1 - uh)];
      while (__hip_atomic_load(fp, __ATOMIC_RELAXED, __HIP_MEMORY_SCOPE_AGENT) == 0)
        __builtin_amdgcn_s_sleep(1);
    }
    __builtin_amdgcn_sched_barrier(0);

    // 6. remote A-fragments direct from hex (coherent), then MFMA
    {
      half8_t rfr[2][4];
#pragma unroll
      for (int rgl = 0; rgl < 2; ++rgl)
#pragma unroll
        for (int kk = 0; kk < 4; ++kk) {
          const _Float16* gp = hex
              + ((size_t)tprev * 64 + rh * 32 + rgl * 16 + l15) * 256
              + ((1 - uh) * 4 + kk) * 32 + lg * 8;
          rfr[rgl][kk] = coh_load16(gp);
        }
      asm volatile("s_waitcnt vmcnt(0)" ::: "memory");
      __builtin_amdgcn_sched_barrier(0);
#pragma unroll
      for (int rgl = 0; rgl < 2; ++rgl)
#pragma unroll
        for (int kk = 0; kk < 4; ++kk)
#pragma unroll
          for (int g = 0; g < 4; ++g)
            acc[rgl][g] = __builtin_amdgcn_mfma_f32_16x16x32_f16(
                rfr[rgl][kk], bfr[(1 - uh) * 4 + kk][g], acc[rgl][g], 0, 0, 0);
    }

    // prefetch pre for next step (hidden under gates + next own phase)
    if (s + 1 < Tt) {
      const int tn = isB ? (Tt - 2 - s) : (s + 1);
      ld_pre(tn, pc);
    }

    // 7. gates -> h(s) -> LDS buf[cur^1]
    GATES_WRITE(acc, (cur ^ 1));
    __syncthreads();
    cur ^= 1;
  }

  // epilogue: publish h(T-1)
  {
    const int tf = isB ? 0 : (Tt - 1);
    const int rr = tid >> 4, ch = tid & 15;
    const int lb = (rr * 256 + ch * 16) ^ ((rr & 7) << 4);
    half8_t v = *(const half8_t*)(hbuf[cur] + lb);
    _Float16* gp = hex + ((size_t)tf * 64 + rh * 32 + rr) * 256 + uh * 128 + ch * 8;
    coh_store16(gp, v);
  }
#undef ACC_INIT
#undef GATES_WRITE
}

// ---------------- VQ: 4 vectors/block, 128 threads (one code per thread) ------
// hex buffers are TIME-indexed: slot t for both directions.
#define VPB 4
__global__ __launch_bounds__(128) void vq_kernel(const _Float16* __restrict__ hexF,
                                                 const _Float16* __restrict__ hexB,
                                                 const float* __restrict__ cb,
                                                 float* __restrict__ q,
                                                 float* __restrict__ dmin) {
  const int tid = threadIdx.x;
  const int v0 = blockIdx.x * VPB;
  __shared__ __align__(16) float zs[VPB][Ee];
  __shared__ float dsh[NCODE];
  __shared__ int ish[NCODE];
  __shared__ int best[VPB];

#pragma unroll
  for (int v = 0; v < VPB; ++v) {
    const int vv = v0 + v;
    const int b = vv >> 9, t = vv & 511;
    const _Float16* hf = hexF + ((size_t)t * 64 + b) * 256;
    const _Float16* hb = hexB + ((size_t)t * 64 + b) * 256;
    zs[v][tid]       = (float)hf[tid];
    zs[v][tid + 128] = (float)hf[tid + 128];
    zs[v][tid + 256] = (float)hb[tid];
    zs[v][tid + 384] = (float)hb[tid + 128];
  }
  __syncthreads();

  float dv[VPB] = {0.0f, 0.0f, 0.0f, 0.0f};
  const float4* crow = (const float4*)(cb + (size_t)tid * Ee);
#pragma unroll 2
  for (int e4 = 0; e4 < Ee / 4; ++e4) {
    float4 cc = crow[e4];
#pragma unroll
    for (int v = 0; v < VPB; ++v) {
      float4 z = *(const float4*)&zs[v][e4 * 4];
      float t0 = z.x - cc.x, t1 = z.y - cc.y, t2 = z.z - cc.z, t3 = z.w - cc.w;
      dv[v] = fmaf(t0, t0, dv[v]);
      dv[v] = fmaf(t1, t1, dv[v]);
      dv[v] = fmaf(t2, t2, dv[v]);
      dv[v] = fmaf(t3, t3, dv[v]);
    }
  }

#pragma unroll
  for (int v = 0; v < VPB; ++v) {
    __syncthreads();
    dsh[tid] = dv[v];
    ish[tid] = tid;
    __syncthreads();
    for (int off = 64; off > 0; off >>= 1) {
      if (tid < off) {
        float dn = dsh[tid + off];
        int in_ = ish[tid + off];
        if (dn < dsh[tid] || (dn == dsh[tid] && in_ < ish[tid])) {
          dsh[tid] = dn;
          ish[tid] = in_;
        }
      }
      __syncthreads();
    }
    if (tid == 0) {
      best[v] = ish[0];
      dmin[v0 + v] = dsh[0];
    }
  }
  __syncthreads();

#pragma unroll
  for (int v = 0; v < VPB; ++v) {
    const float* cbest = cb + (size_t)best[v] * Ee;
    float* qrow = q + (size_t)(v0 + v) * Ee;
#pragma unroll
    for (int u = 0; u < 4; ++u) {
      int e = tid + u * 128;
      float z = zs[v][e];
      qrow[e] = z + (cbest[e] - z);
    }
  }
}

// ---------------- vq loss reduce ----------------
__global__ __launch_bounds__(256) void vq_reduce(const float* __restrict__ dmin,
                                                 float* __restrict__ out) {
  __shared__ float sh[256];
  int tid = threadIdx.x;
  float s = 0.0f;
  for (int i = tid; i < Bb * Tt; i += 256) s += dmin[i];
  sh[tid] = s;
  __syncthreads();
  for (int off = 128; off > 0; off >>= 1) {
    if (tid < off) sh[tid] += sh[tid + off];
    __syncthreads();
  }
  if (tid == 0) out[Bb * NCLS] = sh[0] * (1.25f / ((float)(Bb * Tt) * (float)Ee));
}

// ---------------- decoder backward, single step at t=T-1 (h_prev=c_prev=0) ----
__global__ __launch_bounds__(256) void dec_bwd_last(const float* __restrict__ q,
                                                    const float* __restrict__ wpB,  // [512][256][4]
                                                    const float* __restrict__ bias,
                                                    float* __restrict__ hb_last) {
  int b = blockIdx.x, tid = threadIdx.x;
  __shared__ __align__(16) float zsl[Ee];
  const float* qrow = q + ((size_t)b * Tt + (Tt - 1)) * Ee;
  zsl[tid] = qrow[tid];
  zsl[tid + 256] = qrow[tid + 256];
  __syncthreads();
  float a0 = bias[tid], a1 = bias[256 + tid], a2 = bias[512 + tid], a3 = bias[768 + tid];
  const float4* wp4 = (const float4*)wpB;
#pragma unroll 4
  for (int k = 0; k < Ee; ++k) {
    float zk = zsl[k];
    float4 w = wp4[((size_t)k << 8) + tid];
    a0 = fmaf(zk, w.x, a0); a1 = fmaf(zk, w.y, a1);
    a2 = fmaf(zk, w.z, a2); a3 = fmaf(zk, w.w, a3);
  }
  float i = sigf(a0), f = sigf(a1), g = tanhf(a2), o = sigf(a3);
  (void)f;
  float cc = i * g;
  hb_last[b * Hh + tid] = o * tanhf(cc);
}

// ---------------- classifier ----------------
__global__ __launch_bounds__(256) void classifier_k(const _Float16* __restrict__ hexD,
                                                    const float* __restrict__ hb_last,
                                                    const float* __restrict__ Wcls,
                                                    const float* __restrict__ bcls,
                                                    float* __restrict__ out) {
  int b = blockIdx.x, tid = threadIdx.x;
  __shared__ __align__(16) float dl[Ee];
  dl[tid] = (float)hexD[((size_t)(Tt - 1) * 64 + b) * 256 + tid];
  dl[tid + 256] = hb_last[b * Hh + tid];
  __syncthreads();
  if (tid < NCLS) {
    const float4* wr = (const float4*)(Wcls + (size_t)tid * Ee);
    float acc = bcls[tid];
#pragma unroll 4
    for (int e4 = 0; e4 < Ee / 4; ++e4) {
      float4 w = wr[e4];
      float4 z = *(const float4*)&dl[e4 * 4];
      acc = fmaf(w.x, z.x, acc);
      acc = fmaf(w.y, z.y, acc);
      acc = fmaf(w.z, z.z, acc);
      acc = fmaf(w.w, z.w, acc);
    }
    out[b * NCLS + tid] = acc;
  }
}

// ---------------- launch ----------------
extern "C" void kernel_launch(void* const* d_in, const int* in_sizes, int n_in,
                              void* d_out, int out_size, void* d_ws, size_t ws_size,
                              hipStream_t stream) {
  const float* x     = (const float*)d_in[0];
  const float* eWihF = (const float*)d_in[1];
  const float* eWhhF = (const float*)d_in[2];
  const float* ebF   = (const float*)d_in[3];
  const float* eWihB = (const float*)d_in[4];
  const float* eWhhB = (const float*)d_in[5];
  const float* ebB   = (const float*)d_in[6];
  const float* cb    = (const float*)d_in[7];
  const float* dWihF = (const float*)d_in[8];
  const float* dWhhF = (const float*)d_in[9];
  const float* dbF   = (const float*)d_in[10];
  const float* dWihB = (const float*)d_in[11];
  // d_in[12] = dec_Whh_b: unused (backward decoder state at t=T-1 starts from zero)
  const float* dbB   = (const float*)d_in[13];
  const float* Wcls  = (const float*)d_in[14];
  const float* bcls  = (const float*)d_in[15];
  float* out = (float*)d_out;
  float* w = (float*)d_ws;

  const size_t MR = (size_t)Bb * Tt;                 // 32768
  const size_t SZ_PRE_H = MR * G4 / 2;               // fp16 pre buffer, float units
  const size_t SZ_HEX  = (size_t)Tt * Bb * Hh / 2;   // fp16 exchange, float units
  const size_t SZ_XPAD = MR * INPAD;
  const size_t SZ_WPAD = (size_t)G4 * INPAD;
  const size_t SZ_WPK  = (size_t)512 * G4;
  const size_t SZ_WPH  = (size_t)G4 * Hh / 2;        // fp16 frag pack, float units
  const int NFLG = Tt * 4;                           // per direction (s, rh, uh)

  size_t o = 0;
  __half* preFh = (__half*)(w + o); o += SZ_PRE_H;
  __half* preBh = (__half*)(w + o); o += SZ_PRE_H;
  _Float16* hexF = (_Float16*)(w + o); o += SZ_HEX;
  _Float16* hexB = (_Float16*)(w + o); o += SZ_HEX;
  _Float16* hexD = (_Float16*)(w + o); o += SZ_HEX;
  int* flgF = (int*)(w + o); o += NFLG;
  int* flgB = (int*)(w + o); o += NFLG;
  int* flgD = (int*)(w + o); o += NFLG;
  float* xpad  = w + o; o += SZ_XPAD;
  float* wfpad = w + o; o += SZ_WPAD;
  float* wbpad = w + o; o += SZ_WPAD;
  float* wpkbd = w + o; o += SZ_WPK;
  _Float16* wphF = (_Float16*)(w + o); o += SZ_WPH;
  _Float16* wphB = (_Float16*)(w + o); o += SZ_WPH;
  _Float16* wphD = (_Float16*)(w + o); o += SZ_WPH;
  float* dminp = w + o; o += MR;
  float* hbl   = w + o; o += (size_t)Bb * Hh;
  // aliases over dead regions
  float* quant = (float*)preFh;      // 64 MB fp32 over dead enc preF
  __half* dprf = preBh;              // dec fp16 pre over dead enc preB

  // 1. flags + prep
  hipLaunchKernelGGL(zero_flags_k, dim3((3 * NFLG + 255) / 256), dim3(256), 0, stream,
                     flgF, 3 * NFLG);
  hipLaunchKernelGGL(pad_copy_k, dim3((MR * INPAD) / 256), dim3(256), 0, stream,
                     x, xpad, (int)MR, INRAW, INPAD);
  hipLaunchKernelGGL(pad_copy_k, dim3((G4 * INPAD) / 256), dim3(256), 0, stream,
                     eWihF, wfpad, G4, INRAW, INPAD);
  hipLaunchKernelGGL(pad_copy_k, dim3((G4 * INPAD) / 256), dim3(256), 0, stream,
                     eWihB, wbpad, G4, INRAW, INPAD);
  hipLaunchKernelGGL(pack_w_k, dim3((G4 * 512) / 256), dim3(256), 0, stream, dWihB, wpkbd, 512);
  hipLaunchKernelGGL(pack_w_frag, dim3(1024), dim3(256), 0, stream, eWhhF, wphF);
  hipLaunchKernelGGL(pack_w_frag, dim3(1024), dim3(256), 0, stream, eWhhB, wphB);
  hipLaunchKernelGGL(pack_w_frag, dim3(1024), dim3(256), 0, stream, dWhhF, wphD);

  // 2. encoder input projections
  const dim3 gemmGrid(G4 / BN, MR / BM);
  hipLaunchKernelGGL(gemm_nt_bias_h, gemmGrid, dim3(256), 0, stream,
                     xpad, wfpad, ebF, preFh, (int)MR, G4, INPAD);
  hipLaunchKernelGGL(gemm_nt_bias_h, gemmGrid, dim3(256), 0, stream,
                     xpad, wbpad, ebB, preBh, (int)MR, G4, INPAD);

  // 3. encoder scan: 8 blocks (4 fwd + 4 bwd), 512 threads each
  hipLaunchKernelGGL(lstm_scan_x2, dim3(8), dim3(512), 0, stream,
                     (const half8_t*)preFh, (const half8_t*)wphF, hexF, flgF,
                     (const half8_t*)preBh, (const half8_t*)wphB, hexB, flgB, 4);

  // 4. VQ + loss
  hipLaunchKernelGGL(vq_kernel, dim3(MR / VPB), dim3(128), 0, stream,
                     hexF, hexB, cb, quant, dminp);
  hipLaunchKernelGGL(vq_reduce, dim3(1), dim3(256), 0, stream, dminp, out);

  // 5. decoder fwd input projection
  hipLaunchKernelGGL(gemm_nt_bias_h, gemmGrid, dim3(256), 0, stream,
                     quant, dWihF, dbF, dprf, (int)MR, G4, Ee);

  // 6. decoder bwd (only t=T-1 contributes)
  hipLaunchKernelGGL(dec_bwd_last, dim3(Bb), dim3(256), 0, stream, quant, wpkbd, dbB, hbl);

  // 7. decoder fwd scan: 4 blocks
  hipLaunchKernelGGL(lstm_scan_x2, dim3(4), dim3(512), 0, stream,
                     (const half8_t*)dprf, (const half8_t*)wphD, hexD, flgD,
                     (const half8_t*)dprf, (const half8_t*)wphD, hexD, flgD, 4);

  // 8. classifier
  hipLaunchKernelGGL(classifier_k, dim3(Bb), dim3(256), 0, stream,
                     hexD, hbl, Wcls, bcls, out);
}

// Round 8
// 4102.200 us; speedup vs baseline: 2.9221x; 2.9221x over previous
//
#include <hip/hip_runtime.h>
#include <hip/hip_fp16.h>
#include <cstddef>

#define Bb 64
#define Tt 512
#define INRAW 225
#define Hh 256
#define G4 1024
#define Ee 512
#define NCODE 128
#define NCLS 250

typedef _Float16 half8_t __attribute__((ext_vector_type(8)));
typedef float f32x4 __attribute__((ext_vector_type(4)));

__device__ __forceinline__ float sigf(float x) { return 1.0f / (1.0f + expf(-x)); }
__device__ __forceinline__ float fsig(float x) { return __builtin_amdgcn_rcpf(1.0f + __expf(-x)); }
__device__ __forceinline__ float ftanh(float x) {
  return 2.0f * __builtin_amdgcn_rcpf(1.0f + __expf(-2.0f * x)) - 1.0f;
}

// ---------------- zero flags ----------------
__global__ __launch_bounds__(256) void zero_flags_k(int* __restrict__ p, int n) {
  int i = blockIdx.x * 256 + threadIdx.x;
  if (i < n) __hip_atomic_store(&p[i], 0, __ATOMIC_RELAXED, __HIP_MEMORY_SCOPE_AGENT);
}

// ---------------- x fp32 [32768][225] -> fp16 [32768][256] zero-padded --------
__global__ __launch_bounds__(256) void conv_x_h(const float* __restrict__ src,
                                                _Float16* __restrict__ dst) {
  int idx = blockIdx.x * 256 + threadIdx.x;   // 8,388,608 total
  int row = idx >> 8, k = idx & 255;
  dst[idx] = (k < INRAW) ? (_Float16)src[(size_t)row * INRAW + k] : (_Float16)0.f;
}

// ------- pack W[1024,K] -> wp[k][j(0..255)][g(0..3)] fp32 (dec_bwd only) ------
__global__ __launch_bounds__(256) void pack_w_k(const float* __restrict__ W,
                                                float* __restrict__ wp, int K) {
  int idx = blockIdx.x * 256 + threadIdx.x;   // = jg*K + k
  int jg = idx / K;
  if (jg >= 1024) return;
  int k = idx - jg * K;
  int j = jg >> 2, g = jg & 3;
  wp[(((size_t)k << 8) + j) * 4 + g] = W[(size_t)(g * 256 + j) * K + k];
}

// ------- pack Whh[1024,256] fp32 -> fp16 MFMA B-fragment stream (scan) --------
__global__ __launch_bounds__(256) void pack_w_frag(const float* __restrict__ W,
                                                   _Float16* __restrict__ wp) {
  int idx = blockIdx.x * 256 + threadIdx.x;   // 262144 total
  int e = idx & 7, l = (idx >> 3) & 63, zg = (idx >> 9) & 7;
  int ks = (idx >> 12) & 7, wv = (idx >> 15) & 7;
  int z = zg >> 2, g = zg & 3;
  int u = wv * 32 + z * 16 + (l & 15);
  int k = ks * 32 + (l >> 4) * 8 + e;
  wp[idx] = (_Float16)W[(size_t)(g * 256 + u) * 256 + k];
}

// ------- pack Wih[1024,Kraw] -> fp16 B-frag stream for gemm_mfma_pre ----------
// flat = ((((g*8+w)*2+z)*KS + ks)*64 + l)*8 + e ; k = ks*32+(l>>4)*8+e (0-pad)
__global__ __launch_bounds__(256) void pack_wih_frag(const float* __restrict__ W,
                                                     _Float16* __restrict__ wp,
                                                     int Kraw, int ksbits) {
  int idx = blockIdx.x * 256 + threadIdx.x;
  int KS = 1 << ksbits;
  int e = idx & 7, l = (idx >> 3) & 63;
  int tail = idx >> 9;
  int ks = tail & (KS - 1); tail >>= ksbits;
  int z = tail & 1, w = (tail >> 1) & 7, g = tail >> 4;
  if (g >= 4) return;
  int k = ks * 32 + (l >> 4) * 8 + e;
  int u = w * 32 + z * 16 + (l & 15);
  wp[idx] = (k < Kraw) ? (_Float16)W[(size_t)(g * 256 + u) * Kraw + k] : (_Float16)0.f;
}

// ---- MFMA input-projection GEMM: pre = A @ Wih^T + bias, fragment-layout out.
// grid (t=512, g=4); block 256 = 4 waves (batch-group). K = 256 or 512.
__global__ __launch_bounds__(256) void gemm_mfma_pre(const _Float16* __restrict__ Ah,
                                                     const _Float16* __restrict__ Bp,
                                                     const float* __restrict__ bias,
                                                     __half* __restrict__ C, int K) {
  const int t = blockIdx.x, g = blockIdx.y;
  const int bg = threadIdx.x >> 6;
  const int l = threadIdx.x & 63, l15 = l & 15, lg = l >> 4;
  const int KS = K >> 5;

  f32x4 acc[16];
#pragma unroll
  for (int ct = 0; ct < 16; ++ct) acc[ct] = (f32x4){0.f, 0.f, 0.f, 0.f};

  const _Float16* arow = Ah + ((size_t)(bg * 16 + l15) * 512 + t) * K + lg * 8;

  for (int kh = 0; kh < KS; kh += 8) {
    half8_t af[8];
#pragma unroll
    for (int k2 = 0; k2 < 8; ++k2)
      af[k2] = *(const half8_t*)(arow + (kh + k2) * 32);
#pragma unroll
    for (int ct = 0; ct < 16; ++ct) {
      const int w = ct >> 1, z = ct & 1;
      const _Float16* bb = Bp + ((((size_t)(g * 8 + w) * 2 + z) * KS + kh) * 64 + l) * 8;
#pragma unroll
      for (int k2 = 0; k2 < 8; ++k2) {
        half8_t bf = *(const half8_t*)(bb + (size_t)k2 * 512);
        acc[ct] = __builtin_amdgcn_mfma_f32_16x16x32_f16(af[k2], bf, acc[ct], 0, 0, 0);
      }
    }
  }

#pragma unroll
  for (int ct = 0; ct < 16; ++ct) {
    const int w = ct >> 1, z = ct & 1;
    const int u = w * 32 + z * 16 + l15;
    const float bs = bias[g * 256 + u];
    union { unsigned short us[4]; uint2 u2; } pk;
#pragma unroll
    for (int j = 0; j < 4; ++j) {
      __half hv = __float2half(acc[ct][j] + bs);
      pk.us[j] = *(unsigned short*)&hv;
    }
    __half* dst = C + ((((size_t)t * 4 + bg) * 8 + w) * 2 + z) * 1024 + l * 16 + g * 4;
    *(uint2*)dst = pk.u2;
  }
}

// ------ multi-block LSTM scan (R6, verbatim): 1 wave/block, 16u x 16r --------
__global__ __launch_bounds__(64) void lstm_scan_sync(
    const half8_t* __restrict__ preF, const half8_t* __restrict__ wF,
    _Float16* __restrict__ hexF, int* __restrict__ flgF,
    const half8_t* __restrict__ preB, const half8_t* __restrict__ wB,
    _Float16* __restrict__ hexB, int* __restrict__ flgB, int nfwd) {
  const int isB = (blockIdx.x >= nfwd) ? 1 : 0;
  const half8_t* pre = isB ? preB : preF;
  const half8_t* wfrag = isB ? wB : wF;
  _Float16* hex = isB ? hexB : hexF;
  int* flg = isB ? flgB : flgF;
  const int bid = blockIdx.x - (isB ? nfwd : 0);
  const int rg = bid >> 4, sl = bid & 15;
  const int w_ = sl >> 1, z_ = sl & 1;
  const int l = threadIdx.x, l15 = l & 15, lg = l >> 4;
  const int u0 = sl * 16;

  half8_t bfr[8][4];
#pragma unroll
  for (int ks = 0; ks < 8; ++ks)
#pragma unroll
    for (int g = 0; g < 4; ++g)
      bfr[ks][g] = wfrag[(size_t)((w_ * 8 + ks) * 8 + z_ * 4 + g) * 64 + l];

  float c[4] = {0.f, 0.f, 0.f, 0.f};
  half8_t pc0, pc1;
  {
    const int t0 = isB ? (Tt - 1) : 0;
    const half8_t* pp = pre + ((size_t)(t0 * 4 + rg) * 16 + sl) * 128 + l * 2;
    pc0 = pp[0]; pc1 = pp[1];
  }

  for (int s = 0; s < Tt; ++s) {
    f32x4 acc[4];
#pragma unroll
    for (int g = 0; g < 4; ++g)
#pragma unroll
      for (int j = 0; j < 4; ++j)
        acc[g][j] = (float)((g < 2 ? pc0 : pc1)[(g & 1) * 4 + j]);

    if (s + 1 < Tt) {
      const int tn = isB ? (Tt - 2 - s) : (s + 1);
      const half8_t* pp = pre + ((size_t)(tn * 4 + rg) * 16 + sl) * 128 + l * 2;
      pc0 = pp[0]; pc1 = pp[1];
    }

    if (s > 0) {
      int* fb = flg + ((size_t)(s - 1) * 4 + rg) * 16;
      if (l < 16) {
        while (__hip_atomic_load(&fb[l], __ATOMIC_RELAXED, __HIP_MEMORY_SCOPE_AGENT) == 0)
          __builtin_amdgcn_s_sleep(1);
      }
      const char* ab = (const char*)hex + (((size_t)(s - 1) * 64 + rg * 16) * 256) * 2;
      half8_t afr[8];
#pragma unroll
      for (int ks = 0; ks < 8; ++ks) {
        const void* ap = (const void*)(ab + l15 * 512 + ks * 64 + lg * 16);
        asm volatile("global_load_dwordx4 %0, %1, off sc0 sc1"
                     : "=v"(afr[ks]) : "v"(ap) : "memory");
      }
      asm volatile("s_waitcnt vmcnt(0)" ::: "memory");
      __builtin_amdgcn_sched_barrier(0);

#pragma unroll
      for (int ks = 0; ks < 8; ++ks)
#pragma unroll
        for (int g = 0; g < 4; ++g)
          acc[g] = __builtin_amdgcn_mfma_f32_16x16x32_f16(afr[ks], bfr[ks][g], acc[g], 0, 0, 0);
    }

#pragma unroll
    for (int j = 0; j < 4; ++j) {
      float iv = fsig(acc[0][j]);
      float fv = fsig(acc[1][j]);
      float gv = ftanh(acc[2][j]);
      float ov = fsig(acc[3][j]);
      c[j] = fv * c[j] + iv * gv;
      float hv = ov * ftanh(c[j]);
      union { _Float16 f; unsigned short u; } cv;
      cv.f = (_Float16)hv;
      unsigned hb32 = cv.u;
      const void* hp = (const void*)(hex + ((size_t)s * 64 + rg * 16 + lg * 4 + j) * 256
                                     + u0 + l15);
      asm volatile("global_store_short %0, %1, off sc0 sc1"
                   :: "v"(hp), "v"(hb32) : "memory");
    }

    if (s < Tt - 1) {
      asm volatile("s_waitcnt vmcnt(0)" ::: "memory");
      if (l == 0)
        __hip_atomic_store(&flg[((s)*4 + rg) * 16 + sl - 4 * 16 + 4 * 16], 1,
                           __ATOMIC_RELEASE, __HIP_MEMORY_SCOPE_AGENT);
    }
  }
}

// ---------------- VQ: 4 vectors/block, 128 threads; writes qh fp16 ------------
#define VPB 4
__global__ __launch_bounds__(128) void vq_kernel(const _Float16* __restrict__ hexF,
                                                 const _Float16* __restrict__ hexB,
                                                 const float* __restrict__ cb,
                                                 _Float16* __restrict__ qh,
                                                 float* __restrict__ dmin) {
  const int tid = threadIdx.x;
  const int v0 = blockIdx.x * VPB;
  __shared__ __align__(16) float zs[VPB][Ee];
  __shared__ float dsh[NCODE];
  __shared__ int ish[NCODE];
  __shared__ int best[VPB];

#pragma unroll
  for (int v = 0; v < VPB; ++v) {
    const int vv = v0 + v;
    const int b = vv >> 9, t = vv & 511;
    const _Float16* hf = hexF + ((size_t)t * 64 + b) * 256;
    const _Float16* hb = hexB + ((size_t)(Tt - 1 - t) * 64 + b) * 256;
    zs[v][tid]       = (float)hf[tid];
    zs[v][tid + 128] = (float)hf[tid + 128];
    zs[v][tid + 256] = (float)hb[tid];
    zs[v][tid + 384] = (float)hb[tid + 128];
  }
  __syncthreads();

  float dv[VPB] = {0.0f, 0.0f, 0.0f, 0.0f};
  const float4* crow = (const float4*)(cb + (size_t)tid * Ee);
#pragma unroll 2
  for (int e4 = 0; e4 < Ee / 4; ++e4) {
    float4 cc = crow[e4];
#pragma unroll
    for (int v = 0; v < VPB; ++v) {
      float4 z = *(const float4*)&zs[v][e4 * 4];
      float t0 = z.x - cc.x, t1 = z.y - cc.y, t2 = z.z - cc.z, t3 = z.w - cc.w;
      dv[v] = fmaf(t0, t0, dv[v]);
      dv[v] = fmaf(t1, t1, dv[v]);
      dv[v] = fmaf(t2, t2, dv[v]);
      dv[v] = fmaf(t3, t3, dv[v]);
    }
  }

#pragma unroll
  for (int v = 0; v < VPB; ++v) {
    __syncthreads();
    dsh[tid] = dv[v];
    ish[tid] = tid;
    __syncthreads();
    for (int off = 64; off > 0; off >>= 1) {
      if (tid < off) {
        float dn = dsh[tid + off];
        int in_ = ish[tid + off];
        if (dn < dsh[tid] || (dn == dsh[tid] && in_ < ish[tid])) {
          dsh[tid] = dn;
          ish[tid] = in_;
        }
      }
      __syncthreads();
    }
    if (tid == 0) {
      best[v] = ish[0];
      dmin[v0 + v] = dsh[0];
    }
  }
  __syncthreads();

#pragma unroll
  for (int v = 0; v < VPB; ++v) {
    const float* cbest = cb + (size_t)best[v] * Ee;
    _Float16* qrow = qh + (size_t)(v0 + v) * Ee;
#pragma unroll
    for (int u = 0; u < 4; ++u) {
      int e = tid + u * 128;
      float z = zs[v][e];
      qrow[e] = (_Float16)(z + (cbest[e] - z));
    }
  }
}

// ---------------- vq loss reduce ----------------
__global__ __launch_bounds__(256) void vq_reduce(const float* __restrict__ dmin,
                                                 float* __restrict__ out) {
  __shared__ float sh[256];
  int tid = threadIdx.x;
  float s = 0.0f;
  for (int i = tid; i < Bb * Tt; i += 256) s += dmin[i];
  sh[tid] = s;
  __syncthreads();
  for (int off = 128; off > 0; off >>= 1) {
    if (tid < off) sh[tid] += sh[tid + off];
    __syncthreads();
  }
  if (tid == 0) out[Bb * NCLS] = sh[0] * (1.25f / ((float)(Bb * Tt) * (float)Ee));
}

// ---------------- decoder backward, single step at t=T-1 (h_prev=c_prev=0) ----
__global__ __launch_bounds__(256) void dec_bwd_last(const _Float16* __restrict__ qh,
                                                    const float* __restrict__ wpB,
                                                    const float* __restrict__ bias,
                                                    float* __restrict__ hb_last) {
  int b = blockIdx.x, tid = threadIdx.x;
  __shared__ __align__(16) float zsl[Ee];
  const _Float16* qrow = qh + ((size_t)b * Tt + (Tt - 1)) * Ee;
  zsl[tid] = (float)qrow[tid];
  zsl[tid + 256] = (float)qrow[tid + 256];
  __syncthreads();
  float a0 = bias[tid], a1 = bias[256 + tid], a2 = bias[512 + tid], a3 = bias[768 + tid];
  const float4* wp4 = (const float4*)wpB;
#pragma unroll 4
  for (int k = 0; k < Ee; ++k) {
    float zk = zsl[k];
    float4 w = wp4[((size_t)k << 8) + tid];
    a0 = fmaf(zk, w.x, a0); a1 = fmaf(zk, w.y, a1);
    a2 = fmaf(zk, w.z, a2); a3 = fmaf(zk, w.w, a3);
  }
  float i = sigf(a0), f = sigf(a1), g = tanhf(a2), o = sigf(a3);
  (void)f;
  float cc = i * g;
  hb_last[b * Hh + tid] = o * tanhf(cc);
}

// ---------------- classifier ----------------
__global__ __launch_bounds__(256) void classifier_k(const _Float16* __restrict__ hexD,
                                                    const float* __restrict__ hb_last,
                                                    const float* __restrict__ Wcls,
                                                    const float* __restrict__ bcls,
                                                    float* __restrict__ out) {
  int b = blockIdx.x, tid = threadIdx.x;
  __shared__ __align__(16) float dl[Ee];
  dl[tid] = (float)hexD[((size_t)(Tt - 1) * 64 + b) * 256 + tid];
  dl[tid + 256] = hb_last[b * Hh + tid];
  __syncthreads();
  if (tid < NCLS) {
    const float4* wr = (const float4*)(Wcls + (size_t)tid * Ee);
    float acc = bcls[tid];
#pragma unroll 4
    for (int e4 = 0; e4 < Ee / 4; ++e4) {
      float4 w = wr[e4];
      float4 z = *(const float4*)&dl[e4 * 4];
      acc = fmaf(w.x, z.x, acc);
      acc = fmaf(w.y, z.y, acc);
      acc = fmaf(w.z, z.z, acc);
      acc = fmaf(w.w, z.w, acc);
    }
    out[b * NCLS + tid] = acc;
  }
}

// ---------------- launch ----------------
extern "C" void kernel_launch(void* const* d_in, const int* in_sizes, int n_in,
                              void* d_out, int out_size, void* d_ws, size_t ws_size,
                              hipStream_t stream) {
  const float* x     = (const float*)d_in[0];
  const float* eWihF = (const float*)d_in[1];
  const float* eWhhF = (const float*)d_in[2];
  const float* ebF   = (const float*)d_in[3];
  const float* eWihB = (const float*)d_in[4];
  const float* eWhhB = (const float*)d_in[5];
  const float* ebB   = (const float*)d_in[6];
  const float* cb    = (const float*)d_in[7];
  const float* dWihF = (const float*)d_in[8];
  const float* dWhhF = (const float*)d_in[9];
  const float* dbF   = (const float*)d_in[10];
  const float* dWihB = (const float*)d_in[11];
  // d_in[12] = dec_Whh_b: unused (backward decoder state at t=T-1 starts from zero)
  const float* dbB   = (const float*)d_in[13];
  const float* Wcls  = (const float*)d_in[14];
  const float* bcls  = (const float*)d_in[15];
  float* out = (float*)d_out;
  float* w = (float*)d_ws;

  const size_t MR = (size_t)Bb * Tt;                 // 32768
  const size_t SZ_PRE_H = MR * G4 / 2;               // fp16 pre buffer, float units
  const size_t SZ_HEX  = (size_t)Tt * Bb * Hh / 2;   // fp16 exchange, float units
  const size_t SZ_XH   = MR * 256 / 2;               // xh fp16, float units
  const size_t SZ_WPK  = (size_t)512 * G4;           // dec_bwd fp32 pack
  const size_t SZ_WPH  = (size_t)G4 * Hh / 2;        // Whh frag pack, float units
  const size_t SZ_WIH  = (size_t)4 * 8 * 2 * 8 * 64 * 8 / 2;   // 131072 (enc, KS=8)
  const size_t SZ_WIHD = SZ_WIH * 2;                 // dec, KS=16
  const int NFLG = Tt * 4 * 16;                      // per direction

  size_t o = 0;
  __half* preFh = (__half*)(w + o); o += SZ_PRE_H;
  __half* preBh = (__half*)(w + o); o += SZ_PRE_H;
  _Float16* hexF = (_Float16*)(w + o); o += SZ_HEX;
  _Float16* hexB = (_Float16*)(w + o); o += SZ_HEX;
  _Float16* hexD = (_Float16*)(w + o); o += SZ_HEX;
  int* flgF = (int*)(w + o); o += NFLG;
  int* flgB = (int*)(w + o); o += NFLG;
  int* flgD = (int*)(w + o); o += NFLG;
  _Float16* xh = (_Float16*)(w + o); o += SZ_XH;
  float* wpkbd = w + o; o += SZ_WPK;
  _Float16* wphF = (_Float16*)(w + o); o += SZ_WPH;
  _Float16* wphB = (_Float16*)(w + o); o += SZ_WPH;
  _Float16* wphD = (_Float16*)(w + o); o += SZ_WPH;
  _Float16* wpihF = (_Float16*)(w + o); o += SZ_WIH;
  _Float16* wpihB = (_Float16*)(w + o); o += SZ_WIH;
  _Float16* wpihD = (_Float16*)(w + o); o += SZ_WIHD;
  float* dminp = w + o; o += MR;
  float* hbl   = w + o; o += (size_t)Bb * Hh;
  // aliases over dead regions
  _Float16* qh = (_Float16*)preFh;    // 32 MB fp16 over dead enc preF (post-scan)
  __half* dprf = preBh;               // dec fp16 pre over dead enc preB

  // 1. flags + packs + x conversion
  hipLaunchKernelGGL(zero_flags_k, dim3((3 * NFLG + 255) / 256), dim3(256), 0, stream,
                     flgF, 3 * NFLG);
  hipLaunchKernelGGL(conv_x_h, dim3((int)(MR * 256 / 256)), dim3(256), 0, stream, x, xh);
  hipLaunchKernelGGL(pack_w_k, dim3((G4 * 512) / 256), dim3(256), 0, stream, dWihB, wpkbd, 512);
  hipLaunchKernelGGL(pack_w_frag, dim3(1024), dim3(256), 0, stream, eWhhF, wphF);
  hipLaunchKernelGGL(pack_w_frag, dim3(1024), dim3(256), 0, stream, eWhhB, wphB);
  hipLaunchKernelGGL(pack_w_frag, dim3(1024), dim3(256), 0, stream, dWhhF, wphD);
  hipLaunchKernelGGL(pack_wih_frag, dim3(1024), dim3(256), 0, stream, eWihF, wpihF, INRAW, 3);
  hipLaunchKernelGGL(pack_wih_frag, dim3(1024), dim3(256), 0, stream, eWihB, wpihB, INRAW, 3);
  hipLaunchKernelGGL(pack_wih_frag, dim3(2048), dim3(256), 0, stream, dWihF, wpihD, Ee, 4);

  // 2. encoder input projections (MFMA)
  hipLaunchKernelGGL(gemm_mfma_pre, dim3(Tt, 4), dim3(256), 0, stream,
                     xh, wpihF, ebF, preFh, 256);
  hipLaunchKernelGGL(gemm_mfma_pre, dim3(Tt, 4), dim3(256), 0, stream,
                     xh, wpihB, ebB, preBh, 256);

  // 3. encoder scan: 128 one-wave blocks (64 fwd + 64 bwd)
  hipLaunchKernelGGL(lstm_scan_sync, dim3(128), dim3(64), 0, stream,
                     (const half8_t*)preFh, (const half8_t*)wphF, hexF, flgF,
                     (const half8_t*)preBh, (const half8_t*)wphB, hexB, flgB, 64);

  // 4. VQ + loss (writes qh fp16 over dead preF)
  hipLaunchKernelGGL(vq_kernel, dim3((int)(MR / VPB)), dim3(128), 0, stream,
                     hexF, hexB, cb, qh, dminp);
  hipLaunchKernelGGL(vq_reduce, dim3(1), dim3(256), 0, stream, dminp, out);

  // 5. decoder fwd input projection (MFMA, K=512)
  hipLaunchKernelGGL(gemm_mfma_pre, dim3(Tt, 4), dim3(256), 0, stream,
                     qh, wpihD, dbF, dprf, 512);

  // 6. decoder bwd (only t=T-1 contributes)
  hipLaunchKernelGGL(dec_bwd_last, dim3(Bb), dim3(256), 0, stream, qh, wpkbd, dbB, hbl);

  // 7. decoder fwd scan: 64 one-wave blocks
  hipLaunchKernelGGL(lstm_scan_sync, dim3(64), dim3(64), 0, stream,
                     (const half8_t*)dprf, (const half8_t*)wphD, hexD, flgD,
                     (const half8_t*)dprf, (const half8_t*)wphD, hexD, flgD, 64);

  // 8. classifier
  hipLaunchKernelGGL(classifier_k, dim3(Bb), dim3(256), 0, stream,
                     hexD, hbl, Wcls, bcls, out);
}

// Round 10
// 2573.739 us; speedup vs baseline: 4.6574x; 1.5939x over previous
//
#include <hip/hip_runtime.h>
#include <hip/hip_fp16.h>
#include <cstddef>

#define Bb 64
#define Tt 512
#define INRAW 225
#define Hh 256
#define G4 1024
#define Ee 512
#define NCODE 128
#define NCLS 250

typedef _Float16 half8_t __attribute__((ext_vector_type(8)));
typedef float f32x4 __attribute__((ext_vector_type(4)));

__device__ __forceinline__ float sigf(float x) { return 1.0f / (1.0f + expf(-x)); }
__device__ __forceinline__ float fsig(float x) { return __builtin_amdgcn_rcpf(1.0f + __expf(-x)); }
__device__ __forceinline__ float ftanh(float x) {
  return 2.0f * __builtin_amdgcn_rcpf(1.0f + __expf(-2.0f * x)) - 1.0f;
}

// packed signed-int16 max (VOP3P); fp16 sentinel 0x7C00 is the int16 max among
// {finite |h|<=1 patterns} ∪ {0x7C00}, so a pk_max fold detects any sentinel.
__device__ __forceinline__ unsigned pkmax16(unsigned a, unsigned b) {
  unsigned r;
  asm("v_pk_max_i16 %0, %1, %2" : "=v"(r) : "v"(a), "v"(b));
  return r;
}

// ------- fill hex exchange buffers with fp16 +inf sentinel (coherent stores,
// write-through to L3: no dirty L2 lines that could later clobber scan data) --
__global__ __launch_bounds__(256) void fill_inf_k(unsigned* __restrict__ p, long n) {
  long i = (long)blockIdx.x * 256 + threadIdx.x;
  const long stride = (long)gridDim.x * 256;
  unsigned v = 0x7C007C00u;
  for (; i < n; i += stride) {
    asm volatile("global_store_dword %0, %1, off sc0 sc1" :: "v"(p + i), "v"(v) : "memory");
  }
}

// ---------------- x fp32 [32768][225] -> fp16 [32768][256] zero-padded --------
__global__ __launch_bounds__(256) void conv_x_h(const float* __restrict__ src,
                                                _Float16* __restrict__ dst) {
  int idx = blockIdx.x * 256 + threadIdx.x;   // 8,388,608 total
  int row = idx >> 8, k = idx & 255;
  dst[idx] = (k < INRAW) ? (_Float16)src[(size_t)row * INRAW + k] : (_Float16)0.f;
}

// ------- pack W[1024,K] -> wp[k][j(0..255)][g(0..3)] fp32 (dec_bwd only) ------
__global__ __launch_bounds__(256) void pack_w_k(const float* __restrict__ W,
                                                float* __restrict__ wp, int K) {
  int idx = blockIdx.x * 256 + threadIdx.x;   // = jg*K + k
  int jg = idx / K;
  if (jg >= 1024) return;
  int k = idx - jg * K;
  int j = jg >> 2, g = jg & 3;
  wp[(((size_t)k << 8) + j) * 4 + g] = W[(size_t)(g * 256 + j) * K + k];
}

// ------- pack Whh[1024,256] fp32 -> fp16 MFMA B-fragment stream (scan) --------
__global__ __launch_bounds__(256) void pack_w_frag(const float* __restrict__ W,
                                                   _Float16* __restrict__ wp) {
  int idx = blockIdx.x * 256 + threadIdx.x;   // 262144 total
  int e = idx & 7, l = (idx >> 3) & 63, zg = (idx >> 9) & 7;
  int ks = (idx >> 12) & 7, wv = (idx >> 15) & 7;
  int z = zg >> 2, g = zg & 3;
  int u = wv * 32 + z * 16 + (l & 15);
  int k = ks * 32 + (l >> 4) * 8 + e;
  wp[idx] = (_Float16)W[(size_t)(g * 256 + u) * 256 + k];
}

// ------- pack Wih[1024,Kraw] -> fp16 B-frag stream for gemm_mfma_pre ----------
// flat = ((((g*8+w)*2+z)*KS + ks)*64 + l)*8 + e ; k = ks*32+(l>>4)*8+e (0-pad)
__global__ __launch_bounds__(256) void pack_wih_frag(const float* __restrict__ W,
                                                     _Float16* __restrict__ wp,
                                                     int Kraw, int ksbits) {
  int idx = blockIdx.x * 256 + threadIdx.x;
  int KS = 1 << ksbits;
  int e = idx & 7, l = (idx >> 3) & 63;
  int tail = idx >> 9;
  int ks = tail & (KS - 1); tail >>= ksbits;
  int z = tail & 1, w = (tail >> 1) & 7, g = tail >> 4;
  if (g >= 4) return;
  int k = ks * 32 + (l >> 4) * 8 + e;
  int u = w * 32 + z * 16 + (l & 15);
  wp[idx] = (k < Kraw) ? (_Float16)W[(size_t)(g * 256 + u) * Kraw + k] : (_Float16)0.f;
}

// ---- MFMA input-projection GEMM: pre = A @ Wih^T + bias, fragment-layout out.
// grid (t=512, g=4); block 256 = 4 waves (batch-group). K = 256 or 512.
__global__ __launch_bounds__(256) void gemm_mfma_pre(const _Float16* __restrict__ Ah,
                                                     const _Float16* __restrict__ Bp,
                                                     const float* __restrict__ bias,
                                                     __half* __restrict__ C, int K) {
  const int t = blockIdx.x, g = blockIdx.y;
  const int bg = threadIdx.x >> 6;
  const int l = threadIdx.x & 63, l15 = l & 15, lg = l >> 4;
  const int KS = K >> 5;

  f32x4 acc[16];
#pragma unroll
  for (int ct = 0; ct < 16; ++ct) acc[ct] = (f32x4){0.f, 0.f, 0.f, 0.f};

  const _Float16* arow = Ah + ((size_t)(bg * 16 + l15) * 512 + t) * K + lg * 8;

  for (int kh = 0; kh < KS; kh += 8) {
    half8_t af[8];
#pragma unroll
    for (int k2 = 0; k2 < 8; ++k2)
      af[k2] = *(const half8_t*)(arow + (kh + k2) * 32);
#pragma unroll
    for (int ct = 0; ct < 16; ++ct) {
      const int w = ct >> 1, z = ct & 1;
      const _Float16* bb = Bp + ((((size_t)(g * 8 + w) * 2 + z) * KS + kh) * 64 + l) * 8;
#pragma unroll
      for (int k2 = 0; k2 < 8; ++k2) {
        half8_t bf = *(const half8_t*)(bb + (size_t)k2 * 512);
        acc[ct] = __builtin_amdgcn_mfma_f32_16x16x32_f16(af[k2], bf, acc[ct], 0, 0, 0);
      }
    }
  }

#pragma unroll
  for (int ct = 0; ct < 16; ++ct) {
    const int w = ct >> 1, z = ct & 1;
    const int u = w * 32 + z * 16 + l15;
    const float bs = bias[g * 256 + u];
    union { unsigned short us[4]; uint2 u2; } pk;
#pragma unroll
    for (int j = 0; j < 4; ++j) {
      __half hv = __float2half(acc[ct][j] + bs);
      pk.us[j] = *(unsigned short*)&hv;
    }
    __half* dst = C + ((((size_t)t * 4 + bg) * 8 + w) * 2 + z) * 1024 + l * 16 + g * 4;
    *(uint2*)dst = pk.u2;
  }
}

// ------ multi-block LSTM scan: 1 wave/block, 16 units x 16 rows per block.
// Sync = sentinel-poll on the data itself: hex pre-filled with fp16 +inf;
// producer just stores (coherent); consumer re-loads until no half is inf.
__global__ __launch_bounds__(64) void lstm_scan_sync(
    const half8_t* __restrict__ preF, const half8_t* __restrict__ wF,
    _Float16* __restrict__ hexF,
    const half8_t* __restrict__ preB, const half8_t* __restrict__ wB,
    _Float16* __restrict__ hexB, int nfwd) {
  const int isB = (blockIdx.x >= nfwd) ? 1 : 0;
  const half8_t* pre = isB ? preB : preF;
  const half8_t* wfrag = isB ? wB : wF;
  _Float16* hex = isB ? hexB : hexF;
  const int bid = blockIdx.x - (isB ? nfwd : 0);
  const int rg = bid >> 4, sl = bid & 15;
  const int w_ = sl >> 1, z_ = sl & 1;
  const int l = threadIdx.x, l15 = l & 15, lg = l >> 4;
  const int u0 = sl * 16;

  half8_t bfr[8][4];
#pragma unroll
  for (int ks = 0; ks < 8; ++ks)
#pragma unroll
    for (int g = 0; g < 4; ++g)
      bfr[ks][g] = wfrag[(size_t)((w_ * 8 + ks) * 8 + z_ * 4 + g) * 64 + l];

  float c[4] = {0.f, 0.f, 0.f, 0.f};
  half8_t pc0, pc1;
  {
    const int t0 = isB ? (Tt - 1) : 0;
    const half8_t* pp = pre + ((size_t)(t0 * 4 + rg) * 16 + sl) * 128 + l * 2;
    pc0 = pp[0]; pc1 = pp[1];
  }

  for (int s = 0; s < Tt; ++s) {
    f32x4 acc[4];
#pragma unroll
    for (int g = 0; g < 4; ++g)
#pragma unroll
      for (int j = 0; j < 4; ++j)
        acc[g][j] = (float)((g < 2 ? pc0 : pc1)[(g & 1) * 4 + j]);

    if (s + 1 < Tt) {
      const int tn = isB ? (Tt - 2 - s) : (s + 1);
      const half8_t* pp = pre + ((size_t)(tn * 4 + rg) * 16 + sl) * 128 + l * 2;
      pc0 = pp[0]; pc1 = pp[1];
    }

    if (s > 0) {
      const char* ab = (const char*)hex + (((size_t)(s - 1) * 64 + rg * 16) * 256) * 2;
      half8_t afr[8];
      while (true) {
#pragma unroll
        for (int ks = 0; ks < 8; ++ks) {
          const void* ap = (const void*)(ab + l15 * 512 + ks * 64 + lg * 16);
          asm volatile("global_load_dwordx4 %0, %1, off sc0 sc1"
                       : "=v"(afr[ks]) : "v"(ap) : "memory");
        }
        asm volatile("s_waitcnt vmcnt(0)" ::: "memory");
        // sentinel check via packed int16 max fold (see pkmax16 comment)
        union HU { half8_t h; uint4 u; } cu;
        cu.h = afr[0];
        unsigned mm = pkmax16(pkmax16(cu.u.x, cu.u.y), pkmax16(cu.u.z, cu.u.w));
#pragma unroll
        for (int ks = 1; ks < 8; ++ks) {
          cu.h = afr[ks];
          mm = pkmax16(mm, pkmax16(pkmax16(cu.u.x, cu.u.y), pkmax16(cu.u.z, cu.u.w)));
        }
        int bad = ((mm & 0xFFFFu) == 0x7C00u) || ((mm >> 16) == 0x7C00u);
        if (__all(!bad)) break;
      }
      __builtin_amdgcn_sched_barrier(0);

#pragma unroll
      for (int ks = 0; ks < 8; ++ks)
#pragma unroll
        for (int g = 0; g < 4; ++g)
          acc[g] = __builtin_amdgcn_mfma_f32_16x16x32_f16(afr[ks], bfr[ks][g], acc[g], 0, 0, 0);
    }

    // gates -> c,h; publish h via coherent short stores (no ack wait, no flag)
#pragma unroll
    for (int j = 0; j < 4; ++j) {
      float iv = fsig(acc[0][j]);
      float fv = fsig(acc[1][j]);
      float gv = ftanh(acc[2][j]);
      float ov = fsig(acc[3][j]);
      c[j] = fv * c[j] + iv * gv;
      float hv = ov * ftanh(c[j]);
      union { _Float16 f; unsigned short u; } cv;
      cv.f = (_Float16)hv;
      unsigned hb32 = cv.u;
      const void* hp = (const void*)(hex + ((size_t)s * 64 + rg * 16 + lg * 4 + j) * 256
                                     + u0 + l15);
      asm volatile("global_store_short %0, %1, off sc0 sc1"
                   :: "v"(hp), "v"(hb32) : "memory");
    }
  }
}

// ---------------- VQ: 4 vectors/block, 128 threads; writes qh fp16 ------------
#define VPB 4
__global__ __launch_bounds__(128) void vq_kernel(const _Float16* __restrict__ hexF,
                                                 const _Float16* __restrict__ hexB,
                                                 const float* __restrict__ cb,
                                                 _Float16* __restrict__ qh,
                                                 float* __restrict__ dmin) {
  const int tid = threadIdx.x;
  const int v0 = blockIdx.x * VPB;
  __shared__ __align__(16) float zs[VPB][Ee];
  __shared__ float dsh[NCODE];
  __shared__ int ish[NCODE];
  __shared__ int best[VPB];

#pragma unroll
  for (int v = 0; v < VPB; ++v) {
    const int vv = v0 + v;
    const int b = vv >> 9, t = vv & 511;
    const _Float16* hf = hexF + ((size_t)t * 64 + b) * 256;
    const _Float16* hb = hexB + ((size_t)(Tt - 1 - t) * 64 + b) * 256;
    zs[v][tid]       = (float)hf[tid];
    zs[v][tid + 128] = (float)hf[tid + 128];
    zs[v][tid + 256] = (float)hb[tid];
    zs[v][tid + 384] = (float)hb[tid + 128];
  }
  __syncthreads();

  float dv[VPB] = {0.0f, 0.0f, 0.0f, 0.0f};
  const float4* crow = (const float4*)(cb + (size_t)tid * Ee);
#pragma unroll 2
  for (int e4 = 0; e4 < Ee / 4; ++e4) {
    float4 cc = crow[e4];
#pragma unroll
    for (int v = 0; v < VPB; ++v) {
      float4 z = *(const float4*)&zs[v][e4 * 4];
      float t0 = z.x - cc.x, t1 = z.y - cc.y, t2 = z.z - cc.z, t3 = z.w - cc.w;
      dv[v] = fmaf(t0, t0, dv[v]);
      dv[v] = fmaf(t1, t1, dv[v]);
      dv[v] = fmaf(t2, t2, dv[v]);
      dv[v] = fmaf(t3, t3, dv[v]);
    }
  }

#pragma unroll
  for (int v = 0; v < VPB; ++v) {
    __syncthreads();
    dsh[tid] = dv[v];
    ish[tid] = tid;
    __syncthreads();
    for (int off = 64; off > 0; off >>= 1) {
      if (tid < off) {
        float dn = dsh[tid + off];
        int in_ = ish[tid + off];
        if (dn < dsh[tid] || (dn == dsh[tid] && in_ < ish[tid])) {
          dsh[tid] = dn;
          ish[tid] = in_;
        }
      }
      __syncthreads();
    }
    if (tid == 0) {
      best[v] = ish[0];
      dmin[v0 + v] = dsh[0];
    }
  }
  __syncthreads();

#pragma unroll
  for (int v = 0; v < VPB; ++v) {
    const float* cbest = cb + (size_t)best[v] * Ee;
    _Float16* qrow = qh + (size_t)(v0 + v) * Ee;
#pragma unroll
    for (int u = 0; u < 4; ++u) {
      int e = tid + u * 128;
      float z = zs[v][e];
      qrow[e] = (_Float16)(z + (cbest[e] - z));
    }
  }
}

// ---------------- vq loss reduce ----------------
__global__ __launch_bounds__(256) void vq_reduce(const float* __restrict__ dmin,
                                                 float* __restrict__ out) {
  __shared__ float sh[256];
  int tid = threadIdx.x;
  float s = 0.0f;
  for (int i = tid; i < Bb * Tt; i += 256) s += dmin[i];
  sh[tid] = s;
  __syncthreads();
  for (int off = 128; off > 0; off >>= 1) {
    if (tid < off) sh[tid] += sh[tid + off];
    __syncthreads();
  }
  if (tid == 0) out[Bb * NCLS] = sh[0] * (1.25f / ((float)(Bb * Tt) * (float)Ee));
}

// ---------------- decoder backward, single step at t=T-1 (h_prev=c_prev=0) ----
__global__ __launch_bounds__(256) void dec_bwd_last(const _Float16* __restrict__ qh,
                                                    const float* __restrict__ wpB,
                                                    const float* __restrict__ bias,
                                                    float* __restrict__ hb_last) {
  int b = blockIdx.x, tid = threadIdx.x;
  __shared__ __align__(16) float zsl[Ee];
  const _Float16* qrow = qh + ((size_t)b * Tt + (Tt - 1)) * Ee;
  zsl[tid] = (float)qrow[tid];
  zsl[tid + 256] = (float)qrow[tid + 256];
  __syncthreads();
  float a0 = bias[tid], a1 = bias[256 + tid], a2 = bias[512 + tid], a3 = bias[768 + tid];
  const float4* wp4 = (const float4*)wpB;
#pragma unroll 4
  for (int k = 0; k < Ee; ++k) {
    float zk = zsl[k];
    float4 w = wp4[((size_t)k << 8) + tid];
    a0 = fmaf(zk, w.x, a0); a1 = fmaf(zk, w.y, a1);
    a2 = fmaf(zk, w.z, a2); a3 = fmaf(zk, w.w, a3);
  }
  float i = sigf(a0), f = sigf(a1), g = tanhf(a2), o = sigf(a3);
  (void)f;
  float cc = i * g;
  hb_last[b * Hh + tid] = o * tanhf(cc);
}

// ---------------- classifier ----------------
__global__ __launch_bounds__(256) void classifier_k(const _Float16* __restrict__ hexD,
                                                    const float* __restrict__ hb_last,
                                                    const float* __restrict__ Wcls,
                                                    const float* __restrict__ bcls,
                                                    float* __restrict__ out) {
  int b = blockIdx.x, tid = threadIdx.x;
  __shared__ __align__(16) float dl[Ee];
  dl[tid] = (float)hexD[((size_t)(Tt - 1) * 64 + b) * 256 + tid];
  dl[tid + 256] = hb_last[b * Hh + tid];
  __syncthreads();
  if (tid < NCLS) {
    const float4* wr = (const float4*)(Wcls + (size_t)tid * Ee);
    float acc = bcls[tid];
#pragma unroll 4
    for (int e4 = 0; e4 < Ee / 4; ++e4) {
      float4 w = wr[e4];
      float4 z = *(const float4*)&dl[e4 * 4];
      acc = fmaf(w.x, z.x, acc);
      acc = fmaf(w.y, z.y, acc);
      acc = fmaf(w.z, z.z, acc);
      acc = fmaf(w.w, z.w, acc);
    }
    out[b * NCLS + tid] = acc;
  }
}

// ---------------- launch ----------------
extern "C" void kernel_launch(void* const* d_in, const int* in_sizes, int n_in,
                              void* d_out, int out_size, void* d_ws, size_t ws_size,
                              hipStream_t stream) {
  const float* x     = (const float*)d_in[0];
  const float* eWihF = (const float*)d_in[1];
  const float* eWhhF = (const float*)d_in[2];
  const float* ebF   = (const float*)d_in[3];
  const float* eWihB = (const float*)d_in[4];
  const float* eWhhB = (const float*)d_in[5];
  const float* ebB   = (const float*)d_in[6];
  const float* cb    = (const float*)d_in[7];
  const float* dWihF = (const float*)d_in[8];
  const float* dWhhF = (const float*)d_in[9];
  const float* dbF   = (const float*)d_in[10];
  const float* dWihB = (const float*)d_in[11];
  // d_in[12] = dec_Whh_b: unused (backward decoder state at t=T-1 starts from zero)
  const float* dbB   = (const float*)d_in[13];
  const float* Wcls  = (const float*)d_in[14];
  const float* bcls  = (const float*)d_in[15];
  float* out = (float*)d_out;
  float* w = (float*)d_ws;

  const size_t MR = (size_t)Bb * Tt;                 // 32768
  const size_t SZ_PRE_H = MR * G4 / 2;               // fp16 pre buffer, float units
  const size_t SZ_HEX  = (size_t)Tt * Bb * Hh / 2;   // fp16 exchange, float units
  const size_t SZ_XH   = MR * 256 / 2;               // xh fp16, float units
  const size_t SZ_WPK  = (size_t)512 * G4;           // dec_bwd fp32 pack
  const size_t SZ_WPH  = (size_t)G4 * Hh / 2;        // Whh frag pack, float units
  const size_t SZ_WIH  = (size_t)4 * 8 * 2 * 8 * 64 * 8 / 2;   // 131072 (enc, KS=8)
  const size_t SZ_WIHD = SZ_WIH * 2;                 // dec, KS=16

  size_t o = 0;
  __half* preFh = (__half*)(w + o); o += SZ_PRE_H;
  __half* preBh = (__half*)(w + o); o += SZ_PRE_H;
  _Float16* hexF = (_Float16*)(w + o); o += SZ_HEX;
  _Float16* hexB = (_Float16*)(w + o); o += SZ_HEX;
  _Float16* hexD = (_Float16*)(w + o); o += SZ_HEX;
  _Float16* xh = (_Float16*)(w + o); o += SZ_XH;
  float* wpkbd = w + o; o += SZ_WPK;
  _Float16* wphF = (_Float16*)(w + o); o += SZ_WPH;
  _Float16* wphB = (_Float16*)(w + o); o += SZ_WPH;
  _Float16* wphD = (_Float16*)(w + o); o += SZ_WPH;
  _Float16* wpihF = (_Float16*)(w + o); o += SZ_WIH;
  _Float16* wpihB = (_Float16*)(w + o); o += SZ_WIH;
  _Float16* wpihD = (_Float16*)(w + o); o += SZ_WIHD;
  float* dminp = w + o; o += MR;
  float* hbl   = w + o; o += (size_t)Bb * Hh;
  // aliases over dead regions
  _Float16* qh = (_Float16*)preFh;    // 32 MB fp16 over dead enc preF (post-scan)
  __half* dprf = preBh;               // dec fp16 pre over dead enc preB

  // 1. sentinel fill (hexF|hexB|hexD contiguous) + packs + x conversion
  hipLaunchKernelGGL(fill_inf_k, dim3(2048), dim3(256), 0, stream,
                     (unsigned*)hexF, (long)(3 * SZ_HEX));
  hipLaunchKernelGGL(conv_x_h, dim3((int)(MR * 256 / 256)), dim3(256), 0, stream, x, xh);
  hipLaunchKernelGGL(pack_w_k, dim3((G4 * 512) / 256), dim3(256), 0, stream, dWihB, wpkbd, 512);
  hipLaunchKernelGGL(pack_w_frag, dim3(1024), dim3(256), 0, stream, eWhhF, wphF);
  hipLaunchKernelGGL(pack_w_frag, dim3(1024), dim3(256), 0, stream, eWhhB, wphB);
  hipLaunchKernelGGL(pack_w_frag, dim3(1024), dim3(256), 0, stream, dWhhF, wphD);
  hipLaunchKernelGGL(pack_wih_frag, dim3(1024), dim3(256), 0, stream, eWihF, wpihF, INRAW, 3);
  hipLaunchKernelGGL(pack_wih_frag, dim3(1024), dim3(256), 0, stream, eWihB, wpihB, INRAW, 3);
  hipLaunchKernelGGL(pack_wih_frag, dim3(2048), dim3(256), 0, stream, dWihF, wpihD, Ee, 4);

  // 2. encoder input projections (MFMA)
  hipLaunchKernelGGL(gemm_mfma_pre, dim3(Tt, 4), dim3(256), 0, stream,
                     xh, wpihF, ebF, preFh, 256);
  hipLaunchKernelGGL(gemm_mfma_pre, dim3(Tt, 4), dim3(256), 0, stream,
                     xh, wpihB, ebB, preBh, 256);

  // 3. encoder scan: 128 one-wave blocks (64 fwd + 64 bwd)
  hipLaunchKernelGGL(lstm_scan_sync, dim3(128), dim3(64), 0, stream,
                     (const half8_t*)preFh, (const half8_t*)wphF, hexF,
                     (const half8_t*)preBh, (const half8_t*)wphB, hexB, 64);

  // 4. VQ + loss (writes qh fp16 over dead preF)
  hipLaunchKernelGGL(vq_kernel, dim3((int)(MR / VPB)), dim3(128), 0, stream,
                     hexF, hexB, cb, qh, dminp);
  hipLaunchKernelGGL(vq_reduce, dim3(1), dim3(256), 0, stream, dminp, out);

  // 5. decoder fwd input projection (MFMA, K=512)
  hipLaunchKernelGGL(gemm_mfma_pre, dim3(Tt, 4), dim3(256), 0, stream,
                     qh, wpihD, dbF, dprf, 512);

  // 6. decoder bwd (only t=T-1 contributes)
  hipLaunchKernelGGL(dec_bwd_last, dim3(Bb), dim3(256), 0, stream, qh, wpkbd, dbB, hbl);

  // 7. decoder fwd scan: 64 one-wave blocks
  hipLaunchKernelGGL(lstm_scan_sync, dim3(64), dim3(64), 0, stream,
                     (const half8_t*)dprf, (const half8_t*)wphD, hexD,
                     (const half8_t*)dprf, (const half8_t*)wphD, hexD, 64);

  // 8. classifier
  hipLaunchKernelGGL(classifier_k, dim3(Bb), dim3(256), 0, stream,
                     hexD, hbl, Wcls, bcls, out);
}